// Round 4
// baseline (295.374 us; speedup 1.0000x reference)
//
#include <hip/hip_runtime.h>
#include <stdint.h>

#define BB 4
#define HH 256
#define WW 256
#define CC 128
#define NN 32
#define NPIX (HH*WW)            // 65536
#define RANK 52428u             // 0-based order-stat index: 0.8*(65536-1) exactly
#define TOTAL_PAIRS 1984.0f     // B * N*(N-1)/2
#define CAND_MAX 8192u

// workspace layout: [hist | done | P] zeroed by ONE memset; thr/keys never need zeroing.
// P uses biased parents: stored 0 = sentinel (self-root or background), else parent+1.
#define OFF_HIST 0                               // BB*1024 u32 = 16 KiB (zeroed)
#define OFF_DONE (BB*1024*4)                     // 64 B (zeroed): k_ccl last-block counter
#define OFF_P    (OFF_DONE + 64)                 // BB*NPIX i32 = 1 MiB (zeroed = sentinel)
#define ZERO_BYTES (OFF_P + BB*NPIX*4)
#define OFF_THR  ZERO_BYTES                      // BB u32 (always written)
#define OFF_KEYS (OFF_THR + 64)                  // BB*NPIX u32 = 1 MiB

typedef __attribute__((ext_vector_type(8))) short short8;
typedef __attribute__((ext_vector_type(4))) float f32x4;

// 3-way bf16 split via truncation; residual <= 2^-24 |f|.
__device__ __forceinline__ void split3(float f, short &hi, short &mid, short &lo) {
    uint32_t u  = __float_as_uint(f);
    uint32_t hb = u & 0xffff0000u;
    hi = (short)(hb >> 16);
    float r1 = f - __uint_as_float(hb);
    uint32_t mb = __float_as_uint(r1) & 0xffff0000u;
    mid = (short)(mb >> 16);
    float r2 = r1 - __uint_as_float(mb);
    lo = (short)(__float_as_uint(r2) >> 16);
}

// quantized bin: monotone nondecreasing in d2 (x128 exact pow2 scale) -> exact select.
__device__ __forceinline__ uint32_t qbin_of(uint32_t keybits) {
    float f = __uint_as_float(keybits);
    return (uint32_t)fminf(f * 128.0f, 65535.0f);
}

// ---------------- K0: MFMA min squared distance -> keys + coarse hist ----------------
// block = 256 threads = 4 waves; each wave loops 4 tiles of 16 pixels => 256 px/block.
__global__ __launch_bounds__(256) void k_d2mfma(const float* __restrict__ feat,
        const int* __restrict__ centers, uint32_t* __restrict__ keys,
        uint32_t* __restrict__ hist) {
    __shared__ short gB[12288];      // 24 KiB: [s][tt*4+kk][lane][8]
    __shared__ float gpart[32][8];
    __shared__ float gnormL[32];
    __shared__ uint32_t lhist[1024];
    int b = blockIdx.y;
    int tid = threadIdx.x;

    #pragma unroll
    for (int j = 0; j < 4; j++) lhist[tid + j*256] = 0u;

    // ---- inline gather: thread (n = tid&31, j0 = tid>>5) owns center n, cols [j0*16,+16)
    {
        int n = tid & 31, j0 = tid >> 5;
        int cy = centers[(b*NN + n)*2 + 0];
        int cx = centers[(b*NN + n)*2 + 1];
        const float* gp = feat + ((size_t)(b << 16) + cy*WW + cx)*CC + j0*16;
        int tt = n >> 4, lane16 = n & 15, kk = j0 >> 1, qbase = (j0 & 1)*2;
        float ss = 0.f;
        #pragma unroll
        for (int hh = 0; hh < 2; hh++) {         // two 8-col halves -> q = qbase+hh
            short8 vhi, vmid, vlo;
            #pragma unroll
            for (int u = 0; u < 8; u++) {
                float f = gp[hh*8 + u];
                ss = fmaf(f, f, ss);
                short a, bm, c; split3(f, a, bm, c);
                vhi[u] = a; vmid[u] = bm; vlo[u] = c;
            }
            int lane = (qbase + hh)*16 + lane16;
            int off = (tt*4 + kk)*512 + lane*8;  // shorts; 16B-aligned contiguous
            *(short8*)&gB[off]        = vhi;
            *(short8*)&gB[off + 4096] = vmid;
            *(short8*)&gB[off + 8192] = vlo;
        }
        gpart[n][j0] = ss;
    }
    __syncthreads();
    if (tid < 32) {
        float s = 0.f;
        #pragma unroll
        for (int j = 0; j < 8; j++) s += gpart[tid][j];
        gnormL[tid] = s;
    }
    __syncthreads();

    int wv = tid >> 6, L = tid & 63;
    int m = L & 15, q = L >> 4;
    float gn0 = gnormL[m];
    float gn1 = gnormL[16 + m];

    for (int it = 0; it < 4; it++) {
        int p0 = blockIdx.x*256 + (wv*4 + it)*16;
        const float* fp = feat + ((size_t)(b << 16) + p0 + m)*CC + q*8;

        f32x4 acc[2] = {{0.f,0.f,0.f,0.f},{0.f,0.f,0.f,0.f}};
        float fn = 0.f;

        #pragma unroll
        for (int kk = 0; kk < 4; kk++) {
            float4 fa = *(const float4*)(fp + kk*32);
            float4 fb = *(const float4*)(fp + kk*32 + 4);
            float fs[8] = {fa.x,fa.y,fa.z,fa.w,fb.x,fb.y,fb.z,fb.w};
            short8 ahi, amid, alo;
            #pragma unroll
            for (int j = 0; j < 8; j++) {
                float f = fs[j];
                fn = fmaf(f, f, fn);
                short hh, md, lw; split3(f, hh, md, lw);
                ahi[j] = hh; amid[j] = md; alo[j] = lw;
            }
            #pragma unroll
            for (int t = 0; t < 2; t++) {
                int off = (t*4 + kk)*512 + L*8;
                short8 bhi = *(const short8*)&gB[off];
                short8 bmd = *(const short8*)&gB[off + 4096];
                short8 blo = *(const short8*)&gB[off + 8192];
                // 6 significant split products
                acc[t] = __builtin_amdgcn_mfma_f32_16x16x32_bf16(ahi,  bhi, acc[t], 0,0,0);
                acc[t] = __builtin_amdgcn_mfma_f32_16x16x32_bf16(ahi,  bmd, acc[t], 0,0,0);
                acc[t] = __builtin_amdgcn_mfma_f32_16x16x32_bf16(amid, bhi, acc[t], 0,0,0);
                acc[t] = __builtin_amdgcn_mfma_f32_16x16x32_bf16(ahi,  blo, acc[t], 0,0,0);
                acc[t] = __builtin_amdgcn_mfma_f32_16x16x32_bf16(amid, bmd, acc[t], 0,0,0);
                acc[t] = __builtin_amdgcn_mfma_f32_16x16x32_bf16(alo,  bhi, acc[t], 0,0,0);
            }
        }

        fn += __shfl_xor(fn, 16);
        fn += __shfl_xor(fn, 32);

        // C layout: col(n) = L&15, row(pixel) = q*4 + reg
        float vmin[4];
        #pragma unroll
        for (int r = 0; r < 4; r++) {
            float fnr = __shfl(fn, q*4 + r);
            float d0 = fnr + gn0 - 2.f*acc[0][r];
            float d1 = fnr + gn1 - 2.f*acc[1][r];
            float v = fminf(d0, d1);
            v = fminf(v, __shfl_xor(v, 1));
            v = fminf(v, __shfl_xor(v, 2));
            v = fminf(v, __shfl_xor(v, 4));
            v = fminf(v, __shfl_xor(v, 8));
            vmin[r] = v;
        }
        if (m < 4) {
            float v = (m==0) ? vmin[0] : (m==1) ? vmin[1] : (m==2) ? vmin[2] : vmin[3];
            if (!(v > 0.f)) v = 0.f;     // clamp negatives and -0.0
            uint32_t kb = __float_as_uint(v);
            keys[(size_t)(b << 16) + p0 + q*4 + m] = kb;
            atomicAdd(&lhist[qbin_of(kb) >> 6], 1u);
        }
    }

    __syncthreads();
    #pragma unroll
    for (int j = 0; j < 4; j++) {
        int bin = tid + j*256;
        uint32_t hv = lhist[bin];
        if (hv) atomicAdd(&hist[(b << 10) + bin], hv);
    }
}

// ---------------- K1: single-pass select -> exact threshold key bits ----------------
// one block (1024 thr) per batch. Coarse select from precomputed hist (no key pass),
// then ONE key pass collecting fine hist + coarse-bin candidates simultaneously,
// then compact bin-T candidates (~tens) and exact duplicate-safe rank among them.
__global__ __launch_bounds__(1024) void k_selthr(const uint32_t* __restrict__ keys,
        const uint32_t* __restrict__ hist, uint32_t* __restrict__ thr_sm) {
    int b = blockIdx.x, t = threadIdx.x;
    __shared__ uint32_t wsum[16];
    __shared__ uint32_t sT1, sR1, sT, sR2, scnt, scnt2;
    __shared__ uint32_t fh[64];
    __shared__ uint32_t cand[CAND_MAX];
    __shared__ uint32_t cand2[2048];

    if (t < 64) fh[t] = 0;
    if (t == 0) { scnt = 0; scnt2 = 0; }

    // coarse select T1: prefix over 1024 precomputed bins (wave scan + cross-wave fix)
    int lane = t & 63, w = t >> 6;
    uint32_t s = hist[(b << 10) + t];
    uint32_t inc = s;
    #pragma unroll
    for (int off = 1; off < 64; off <<= 1) {
        uint32_t nb = __shfl_up((int)inc, off);
        if (lane >= off) inc += nb;
    }
    if (lane == 63) wsum[w] = inc;
    __syncthreads();
    if (t < 16) {
        uint32_t v = wsum[t];
        #pragma unroll
        for (int off = 1; off < 16; off <<= 1) {
            uint32_t nb = __shfl_up((int)v, off);
            if (t >= off) v += nb;
        }
        wsum[t] = v;
    }
    __syncthreads();
    uint32_t pre = ((w == 0) ? 0u : wsum[w-1]) + inc - s;
    if (pre <= RANK && RANK < pre + s) { sT1 = (uint32_t)t; sR1 = RANK - pre; }
    __syncthreads();
    uint32_t T1 = sT1, r1 = sR1;

    // single pass: fine hist (qbin&63) + candidate collection for qbin>>6 == T1
    const uint4* kb = (const uint4*)(keys + ((size_t)b << 16));
    for (int i = t; i < NPIX/4; i += 1024) {
        uint4 k = kb[i];
        uint32_t q;
        #define PROC_KEY(X) { q = qbin_of(X); if ((q >> 6) == T1) { \
            atomicAdd(&fh[q & 63u], 1u); \
            uint32_t p = atomicAdd(&scnt, 1u); \
            if (p < CAND_MAX) cand[p] = (X); } }
        PROC_KEY(k.x) PROC_KEY(k.y) PROC_KEY(k.z) PROC_KEY(k.w)
        #undef PROC_KEY
    }
    __syncthreads();

    // fine select T
    if (t < 64) {
        uint32_t s2 = fh[t];
        uint32_t inc2 = s2;
        #pragma unroll
        for (int off = 1; off < 64; off <<= 1) {
            uint32_t nb = __shfl_up((int)inc2, off);
            if (t >= off) inc2 += nb;
        }
        uint32_t pre2 = inc2 - s2;
        if (pre2 <= r1 && r1 < pre2 + s2) { sT = (T1 << 6) | (uint32_t)t; sR2 = r1 - pre2; }
    }
    __syncthreads();
    uint32_t T = sT, r2 = sR2;
    uint32_t K = scnt; if (K > CAND_MAX) K = CAND_MAX;

    // compact bin-T candidates (expected ~tens)
    for (uint32_t i = t; i < K; i += 1024) {
        uint32_t v = cand[i];
        if (qbin_of(v) == T) { uint32_t p = atomicAdd(&scnt2, 1u); if (p < 2048u) cand2[p] = v; }
    }
    __syncthreads();
    uint32_t K2 = scnt2; if (K2 > 2048u) K2 = 2048u;

    // exact rank among bin-T candidates (duplicate-safe)
    for (uint32_t i = t; i < K2; i += 1024) {
        uint32_t v = cand2[i];
        uint32_t less = 0, eq = 0;
        for (uint32_t j = 0; j < K2; j++) { uint32_t x = cand2[j]; less += (x < v); eq += (x == v); }
        if (less <= r2 && r2 < less + eq) thr_sm[b] = v;   // all writers agree
    }
}

// ---------------- union-find with biased parents (0 = self-root sentinel) ----------
// parent pointers always point to smaller indices -> chains strictly decrease, no cycles.
__device__ __forceinline__ int uf_find(int* P, int x) {
    while (true) {
        int v = P[x];
        if (v == 0) return x;
        int p = v - 1;
        int gv = P[p];
        if (gv == 0) return p;
        P[x] = gv;             // path halving (benign race, always a valid ancestor link)
        x = gv - 1;
    }
}
__device__ __forceinline__ void uf_unite(int* P, int a, int b) {
    while (true) {
        a = uf_find(P, a);
        b = uf_find(P, b);
        if (a == b) return;
        if (a > b) { int t = a; a = b; b = t; }
        int old = atomicCAS(&P[b], 0, a + 1);   // device-scope
        if (old == 0) return;
        b = old - 1;
    }
}

// ---------------- K2: fused CCL: on-the-fly run-starts + unions + last-block pairs ----
// block = one image row (1024 blocks). Run-start labels are a pure function of keys,
// recomputed for own row and the row above -> no separate init kernel needed.
// P stores: non-run-start masked pixels get P[p]=runstart+1 (plain store; these addresses
// are never touched by CAS/path-halving, which traverse run-start nodes only).
// Last block (device-scope done counter) resolves centers and writes the output.
__global__ __launch_bounds__(256) void k_ccl(const uint32_t* __restrict__ keys,
        const uint32_t* __restrict__ thr_sm, const int* __restrict__ centers,
        int* __restrict__ Pg, uint32_t* __restrict__ done, float* __restrict__ out) {
    int bid = blockIdx.x;
    int b = bid >> 8, rr = bid & 255;
    int x = threadIdx.x;
    __shared__ int up_rs[256];     // upper row: global run-start index, or -1 if unmasked
    __shared__ int swtmp[4];
    __shared__ int ids[BB*NN];
    __shared__ int stotal;
    __shared__ bool isLast;

    uint32_t thrv = thr_sm[b];
    int* P = Pg + (b << 16);
    int p = (rr << 8) + x;
    bool msk = keys[((size_t)b << 16) + p] >= thrv;
    int lane = x & 63, w = x >> 6;

    // scan own row: nearest unmasked index <= x  ->  run start = acc+1
    int v = msk ? -1 : x;
    #pragma unroll
    for (int off = 1; off < 64; off <<= 1) {
        int nb = __shfl_up(v, off);
        if (lane >= off) v = max(v, nb);
    }
    if (lane == 63) swtmp[w] = v;
    __syncthreads();
    int acc = v;
    for (int i = 0; i < w; i++) acc = max(acc, swtmp[i]);
    int rs = (rr << 8) + acc + 1;            // valid only when msk
    __syncthreads();                          // before reusing swtmp

    if (rr > 0) {
        bool msku = keys[((size_t)b << 16) + p - WW] >= thrv;
        int vu = msku ? -1 : x;
        #pragma unroll
        for (int off = 1; off < 64; off <<= 1) {
            int nb = __shfl_up(vu, off);
            if (lane >= off) vu = max(vu, nb);
        }
        if (lane == 63) swtmp[w] = vu;
        __syncthreads();
        int accu = vu;
        for (int i = 0; i < w; i++) accu = max(accu, swtmp[i]);
        up_rs[x] = msku ? (((rr - 1) << 8) + accu + 1) : -1;
    }

    if (msk && rs != p) P[p] = rs + 1;       // init store (disjoint from CAS targets)
    __syncthreads();                          // up_rs ready

    if (rr > 0 && msk) {
        bool ul = (x > 0)   && up_rs[x-1] >= 0;
        bool uu =              up_rs[x]   >= 0;
        bool ur = (x < 255) && up_rs[x+1] >= 0;
        if (ul)        uf_unite(P, rs, up_rs[x-1]);
        if (uu && !ul) uf_unite(P, rs, up_rs[x]);
        if (ur && !uu) uf_unite(P, rs, up_rs[x+1]);
    }

    // publish all stores, then last-arriving block finishes the reduction
    __threadfence();
    __syncthreads();
    if (x == 0) { uint32_t d = atomicAdd(done, 1u); isLast = (d == 1023u); }
    __syncthreads();
    if (!isLast) return;
    __threadfence();

    // ---- pairs at centers + output
    if (x == 0) stotal = 0;
    __syncthreads();
    if (x < BB*NN) {
        int bb = x >> 5;
        int cy = centers[x*2 + 0];
        int cx = centers[x*2 + 1];
        int pp = cy*WW + cx;
        const int* Pb = Pg + (bb << 16);
        int id = -1;
        if (keys[((size_t)bb << 16) + pp] >= thr_sm[bb]) {
            int xx = pp;
            while (true) { int vv = Pb[xx]; if (vv == 0) break; xx = vv - 1; }
            id = xx;
        }
        ids[x] = id;
    }
    __syncthreads();
    int cnt = 0;
    if (x < BB*NN) {
        int bb = x >> 5, n = x & 31;
        int id = ids[x];
        if (id != -1) for (int j = n + 1; j < NN; j++) cnt += (ids[bb*NN + j] == id);
    }
    if (cnt) atomicAdd(&stotal, cnt);
    __syncthreads();
    if (x == 0) out[0] = (float)stotal / TOTAL_PAIRS;
}

extern "C" void kernel_launch(void* const* d_in, const int* in_sizes, int n_in,
                              void* d_out, int out_size, void* d_ws, size_t ws_size,
                              hipStream_t stream) {
    const float* feat  = (const float*)d_in[0];
    const int* centers = (const int*)d_in[1];
    float* out         = (float*)d_out;
    char* ws           = (char*)d_ws;

    uint32_t* hist = (uint32_t*)(ws + OFF_HIST);
    uint32_t* done = (uint32_t*)(ws + OFF_DONE);
    int*      Pg   = (int*)(ws + OFF_P);
    uint32_t* thr  = (uint32_t*)(ws + OFF_THR);
    uint32_t* keys = (uint32_t*)(ws + OFF_KEYS);

    hipMemsetAsync(ws, 0, ZERO_BYTES, stream);   // hist + done + P sentinel in one fill

    dim3 gridPix(NPIX/256, BB);
    k_d2mfma <<<gridPix, 256, 0, stream>>>(feat, centers, keys, hist);
    k_selthr <<<BB, 1024, 0, stream>>>(keys, hist, thr);
    k_ccl    <<<HH*BB, 256, 0, stream>>>(keys, thr, centers, Pg, done, out);
}

// Round 5
// 227.374 us; speedup vs baseline: 1.2991x; 1.2991x over previous
//
#include <hip/hip_runtime.h>
#include <stdint.h>

#define BB 4
#define HH 256
#define WW 256
#define CC 128
#define NN 32
#define NPIX (HH*WW)            // 65536
#define RANK 52428u             // 0-based order-stat index: 0.8*(65536-1) exactly
#define TOTAL_PAIRS 1984.0f     // B * N*(N-1)/2
#define CAND_MAX 8192u

// workspace layout: only hist needs zeroing (16 KiB memset). P is zeroed inline by K0.
// P uses biased parents: stored 0 = sentinel (self-root or background), else parent+1.
#define OFF_HIST 0                               // BB*1024 u32 = 16 KiB (zeroed)
#define ZERO_BYTES (BB*1024*4)
#define OFF_THR  ZERO_BYTES                      // BB u32 (always written)
#define OFF_P    (OFF_THR + 64)                  // BB*NPIX i32 = 1 MiB (zeroed by K0)
#define OFF_KEYS (OFF_P + BB*NPIX*4)             // BB*NPIX u32 = 1 MiB

typedef __attribute__((ext_vector_type(8))) short short8;
typedef __attribute__((ext_vector_type(4))) float f32x4;

// 3-way bf16 split via truncation; residual <= 2^-24 |f|.
__device__ __forceinline__ void split3(float f, short &hi, short &mid, short &lo) {
    uint32_t u  = __float_as_uint(f);
    uint32_t hb = u & 0xffff0000u;
    hi = (short)(hb >> 16);
    float r1 = f - __uint_as_float(hb);
    uint32_t mb = __float_as_uint(r1) & 0xffff0000u;
    mid = (short)(mb >> 16);
    float r2 = r1 - __uint_as_float(mb);
    lo = (short)(__float_as_uint(r2) >> 16);
}

// quantized bin: monotone nondecreasing in d2 (x128 exact pow2 scale) -> exact select.
__device__ __forceinline__ uint32_t qbin_of(uint32_t keybits) {
    float f = __uint_as_float(keybits);
    return (uint32_t)fminf(f * 128.0f, 65535.0f);
}

// ---------------- K0: MFMA min squared distance -> keys + coarse hist + P zeroing -----
// block = 256 threads = 4 waves; each wave loops 4 tiles of 16 pixels => 256 px/block.
__global__ __launch_bounds__(256) void k_d2mfma(const float* __restrict__ feat,
        const int* __restrict__ centers, uint32_t* __restrict__ keys,
        uint32_t* __restrict__ hist, int* __restrict__ Pg) {
    __shared__ short gB[12288];      // 24 KiB: [s][tt*4+kk][lane][8]
    __shared__ float gpart[32][8];
    __shared__ float gnormL[32];
    __shared__ uint32_t lhist[1024];
    int b = blockIdx.y;
    int tid = threadIdx.x;

    // zero this block's P slice (dense coalesced; consumed only after kernel boundary)
    Pg[(b << 16) + blockIdx.x*256 + tid] = 0;

    #pragma unroll
    for (int j = 0; j < 4; j++) lhist[tid + j*256] = 0u;

    // ---- inline gather: thread (n = tid&31, j0 = tid>>5) owns center n, cols [j0*16,+16)
    {
        int n = tid & 31, j0 = tid >> 5;
        int cy = centers[(b*NN + n)*2 + 0];
        int cx = centers[(b*NN + n)*2 + 1];
        const float* gp = feat + ((size_t)(b << 16) + cy*WW + cx)*CC + j0*16;
        int tt = n >> 4, lane16 = n & 15, kk = j0 >> 1, qbase = (j0 & 1)*2;
        float ss = 0.f;
        #pragma unroll
        for (int hh = 0; hh < 2; hh++) {         // two 8-col halves -> q = qbase+hh
            short8 vhi, vmid, vlo;
            #pragma unroll
            for (int u = 0; u < 8; u++) {
                float f = gp[hh*8 + u];
                ss = fmaf(f, f, ss);
                short a, bm, c; split3(f, a, bm, c);
                vhi[u] = a; vmid[u] = bm; vlo[u] = c;
            }
            int lane = (qbase + hh)*16 + lane16;
            int off = (tt*4 + kk)*512 + lane*8;  // shorts; 16B-aligned contiguous
            *(short8*)&gB[off]        = vhi;
            *(short8*)&gB[off + 4096] = vmid;
            *(short8*)&gB[off + 8192] = vlo;
        }
        gpart[n][j0] = ss;
    }
    __syncthreads();
    if (tid < 32) {
        float s = 0.f;
        #pragma unroll
        for (int j = 0; j < 8; j++) s += gpart[tid][j];
        gnormL[tid] = s;
    }
    __syncthreads();

    int wv = tid >> 6, L = tid & 63;
    int m = L & 15, q = L >> 4;
    float gn0 = gnormL[m];
    float gn1 = gnormL[16 + m];

    for (int it = 0; it < 4; it++) {
        int p0 = blockIdx.x*256 + (wv*4 + it)*16;
        const float* fp = feat + ((size_t)(b << 16) + p0 + m)*CC + q*8;

        f32x4 acc[2] = {{0.f,0.f,0.f,0.f},{0.f,0.f,0.f,0.f}};
        float fn = 0.f;

        #pragma unroll
        for (int kk = 0; kk < 4; kk++) {
            float4 fa = *(const float4*)(fp + kk*32);
            float4 fb = *(const float4*)(fp + kk*32 + 4);
            float fs[8] = {fa.x,fa.y,fa.z,fa.w,fb.x,fb.y,fb.z,fb.w};
            short8 ahi, amid, alo;
            #pragma unroll
            for (int j = 0; j < 8; j++) {
                float f = fs[j];
                fn = fmaf(f, f, fn);
                short hh, md, lw; split3(f, hh, md, lw);
                ahi[j] = hh; amid[j] = md; alo[j] = lw;
            }
            #pragma unroll
            for (int t = 0; t < 2; t++) {
                int off = (t*4 + kk)*512 + L*8;
                short8 bhi = *(const short8*)&gB[off];
                short8 bmd = *(const short8*)&gB[off + 4096];
                short8 blo = *(const short8*)&gB[off + 8192];
                // 6 significant split products
                acc[t] = __builtin_amdgcn_mfma_f32_16x16x32_bf16(ahi,  bhi, acc[t], 0,0,0);
                acc[t] = __builtin_amdgcn_mfma_f32_16x16x32_bf16(ahi,  bmd, acc[t], 0,0,0);
                acc[t] = __builtin_amdgcn_mfma_f32_16x16x32_bf16(amid, bhi, acc[t], 0,0,0);
                acc[t] = __builtin_amdgcn_mfma_f32_16x16x32_bf16(ahi,  blo, acc[t], 0,0,0);
                acc[t] = __builtin_amdgcn_mfma_f32_16x16x32_bf16(amid, bmd, acc[t], 0,0,0);
                acc[t] = __builtin_amdgcn_mfma_f32_16x16x32_bf16(alo,  bhi, acc[t], 0,0,0);
            }
        }

        fn += __shfl_xor(fn, 16);
        fn += __shfl_xor(fn, 32);

        // C layout: col(n) = L&15, row(pixel) = q*4 + reg
        float vmin[4];
        #pragma unroll
        for (int r = 0; r < 4; r++) {
            float fnr = __shfl(fn, q*4 + r);
            float d0 = fnr + gn0 - 2.f*acc[0][r];
            float d1 = fnr + gn1 - 2.f*acc[1][r];
            float v = fminf(d0, d1);
            v = fminf(v, __shfl_xor(v, 1));
            v = fminf(v, __shfl_xor(v, 2));
            v = fminf(v, __shfl_xor(v, 4));
            v = fminf(v, __shfl_xor(v, 8));
            vmin[r] = v;
        }
        if (m < 4) {
            float v = (m==0) ? vmin[0] : (m==1) ? vmin[1] : (m==2) ? vmin[2] : vmin[3];
            if (!(v > 0.f)) v = 0.f;     // clamp negatives and -0.0
            uint32_t kb = __float_as_uint(v);
            keys[(size_t)(b << 16) + p0 + q*4 + m] = kb;
            atomicAdd(&lhist[qbin_of(kb) >> 6], 1u);
        }
    }

    __syncthreads();
    #pragma unroll
    for (int j = 0; j < 4; j++) {
        int bin = tid + j*256;
        uint32_t hv = lhist[bin];
        if (hv) atomicAdd(&hist[(b << 10) + bin], hv);
    }
}

// ---------------- K1: single-pass select -> exact threshold key bits ----------------
// one block (1024 thr) per batch. Coarse select from precomputed hist (no key pass),
// then ONE key pass collecting fine hist + coarse-bin candidates simultaneously,
// then compact bin-T candidates (~tens) and exact duplicate-safe rank among them.
__global__ __launch_bounds__(1024) void k_selthr(const uint32_t* __restrict__ keys,
        const uint32_t* __restrict__ hist, uint32_t* __restrict__ thr_sm) {
    int b = blockIdx.x, t = threadIdx.x;
    __shared__ uint32_t wsum[16];
    __shared__ uint32_t sT1, sR1, sT, sR2, scnt, scnt2;
    __shared__ uint32_t fh[64];
    __shared__ uint32_t cand[CAND_MAX];
    __shared__ uint32_t cand2[2048];

    if (t < 64) fh[t] = 0;
    if (t == 0) { scnt = 0; scnt2 = 0; }

    // coarse select T1: prefix over 1024 precomputed bins (wave scan + cross-wave fix)
    int lane = t & 63, w = t >> 6;
    uint32_t s = hist[(b << 10) + t];
    uint32_t inc = s;
    #pragma unroll
    for (int off = 1; off < 64; off <<= 1) {
        uint32_t nb = __shfl_up((int)inc, off);
        if (lane >= off) inc += nb;
    }
    if (lane == 63) wsum[w] = inc;
    __syncthreads();
    if (t < 16) {
        uint32_t v = wsum[t];
        #pragma unroll
        for (int off = 1; off < 16; off <<= 1) {
            uint32_t nb = __shfl_up((int)v, off);
            if (t >= off) v += nb;
        }
        wsum[t] = v;
    }
    __syncthreads();
    uint32_t pre = ((w == 0) ? 0u : wsum[w-1]) + inc - s;
    if (pre <= RANK && RANK < pre + s) { sT1 = (uint32_t)t; sR1 = RANK - pre; }
    __syncthreads();
    uint32_t T1 = sT1, r1 = sR1;

    // single pass: fine hist (qbin&63) + candidate collection for qbin>>6 == T1
    const uint4* kb = (const uint4*)(keys + ((size_t)b << 16));
    for (int i = t; i < NPIX/4; i += 1024) {
        uint4 k = kb[i];
        uint32_t q;
        #define PROC_KEY(X) { q = qbin_of(X); if ((q >> 6) == T1) { \
            atomicAdd(&fh[q & 63u], 1u); \
            uint32_t p = atomicAdd(&scnt, 1u); \
            if (p < CAND_MAX) cand[p] = (X); } }
        PROC_KEY(k.x) PROC_KEY(k.y) PROC_KEY(k.z) PROC_KEY(k.w)
        #undef PROC_KEY
    }
    __syncthreads();

    // fine select T
    if (t < 64) {
        uint32_t s2 = fh[t];
        uint32_t inc2 = s2;
        #pragma unroll
        for (int off = 1; off < 64; off <<= 1) {
            uint32_t nb = __shfl_up((int)inc2, off);
            if (t >= off) inc2 += nb;
        }
        uint32_t pre2 = inc2 - s2;
        if (pre2 <= r1 && r1 < pre2 + s2) { sT = (T1 << 6) | (uint32_t)t; sR2 = r1 - pre2; }
    }
    __syncthreads();
    uint32_t T = sT, r2 = sR2;
    uint32_t K = scnt; if (K > CAND_MAX) K = CAND_MAX;

    // compact bin-T candidates (expected ~tens)
    for (uint32_t i = t; i < K; i += 1024) {
        uint32_t v = cand[i];
        if (qbin_of(v) == T) { uint32_t p = atomicAdd(&scnt2, 1u); if (p < 2048u) cand2[p] = v; }
    }
    __syncthreads();
    uint32_t K2 = scnt2; if (K2 > 2048u) K2 = 2048u;

    // exact rank among bin-T candidates (duplicate-safe)
    for (uint32_t i = t; i < K2; i += 1024) {
        uint32_t v = cand2[i];
        uint32_t less = 0, eq = 0;
        for (uint32_t j = 0; j < K2; j++) { uint32_t x = cand2[j]; less += (x < v); eq += (x == v); }
        if (less <= r2 && r2 < less + eq) thr_sm[b] = v;   // all writers agree
    }
}

// ---------------- union-find with biased parents (0 = self-root sentinel) ----------
// parent pointers always point to smaller indices -> chains strictly decrease, no cycles.
__device__ __forceinline__ int uf_find(int* P, int x) {
    while (true) {
        int v = P[x];
        if (v == 0) return x;
        int p = v - 1;
        int gv = P[p];
        if (gv == 0) return p;
        P[x] = gv;             // path halving (benign race, always a valid ancestor link)
        x = gv - 1;
    }
}
__device__ __forceinline__ void uf_unite(int* P, int a, int b) {
    while (true) {
        a = uf_find(P, a);
        b = uf_find(P, b);
        if (a == b) return;
        if (a > b) { int t = a; a = b; b = t; }
        int old = atomicCAS(&P[b], 0, a + 1);   // device-scope
        if (old == 0) return;
        b = old - 1;
    }
}

// ---------------- K2: fused CCL: on-the-fly run-starts + unions (NO gate) -------------
// block = one image row (1024 blocks). Run-start labels are a pure function of keys,
// recomputed for own row and the row above -> no separate init kernel needed.
// P stores: non-run-start masked pixels get P[p]=runstart+1 (plain store; these addresses
// are never touched by CAS/path-halving, which traverse run-start nodes only).
__global__ __launch_bounds__(256) void k_ccl(const uint32_t* __restrict__ keys,
        const uint32_t* __restrict__ thr_sm, int* __restrict__ Pg) {
    int bid = blockIdx.x;
    int b = bid >> 8, rr = bid & 255;
    int x = threadIdx.x;
    __shared__ int up_rs[256];     // upper row: global run-start index, or -1 if unmasked
    __shared__ int swtmp[4];

    uint32_t thrv = thr_sm[b];
    int* P = Pg + (b << 16);
    int p = (rr << 8) + x;
    bool msk = keys[((size_t)b << 16) + p] >= thrv;
    int lane = x & 63, w = x >> 6;

    // scan own row: nearest unmasked index <= x  ->  run start = acc+1
    int v = msk ? -1 : x;
    #pragma unroll
    for (int off = 1; off < 64; off <<= 1) {
        int nb = __shfl_up(v, off);
        if (lane >= off) v = max(v, nb);
    }
    if (lane == 63) swtmp[w] = v;
    __syncthreads();
    int acc = v;
    for (int i = 0; i < w; i++) acc = max(acc, swtmp[i]);
    int rs = (rr << 8) + acc + 1;            // valid only when msk
    __syncthreads();                          // before reusing swtmp

    if (rr > 0) {
        bool msku = keys[((size_t)b << 16) + p - WW] >= thrv;
        int vu = msku ? -1 : x;
        #pragma unroll
        for (int off = 1; off < 64; off <<= 1) {
            int nb = __shfl_up(vu, off);
            if (lane >= off) vu = max(vu, nb);
        }
        if (lane == 63) swtmp[w] = vu;
        __syncthreads();
        int accu = vu;
        for (int i = 0; i < w; i++) accu = max(accu, swtmp[i]);
        up_rs[x] = msku ? (((rr - 1) << 8) + accu + 1) : -1;
    }

    if (msk && rs != p) P[p] = rs + 1;       // init store (disjoint from CAS targets)
    __syncthreads();                          // up_rs ready

    if (rr > 0 && msk) {
        bool ul = (x > 0)   && up_rs[x-1] >= 0;
        bool uu =              up_rs[x]   >= 0;
        bool ur = (x < 255) && up_rs[x+1] >= 0;
        if (ul)        uf_unite(P, rs, up_rs[x-1]);
        if (uu && !ul) uf_unite(P, rs, up_rs[x]);
        if (ur && !uu) uf_unite(P, rs, up_rs[x+1]);
    }
}

// ---------------- K3: merged pairs at centers + output ----------------
__global__ void k_pairs_fin(const int* __restrict__ centers,
        const uint32_t* __restrict__ keys, const uint32_t* __restrict__ thr_sm,
        const int* __restrict__ Pg, float* __restrict__ out) {
    __shared__ int ids[BB*NN];
    __shared__ int total;
    int t = threadIdx.x;
    if (t == 0) total = 0;
    __syncthreads();
    if (t < BB*NN) {
        int bb = t >> 5;
        int cy = centers[t*2 + 0];
        int cx = centers[t*2 + 1];
        int pp = cy*WW + cx;
        const int* Pb = Pg + (bb << 16);
        int id = -1;
        if (keys[((size_t)bb << 16) + pp] >= thr_sm[bb]) {
            int xx = pp;
            while (true) { int vv = Pb[xx]; if (vv == 0) break; xx = vv - 1; }
            id = xx;
        }
        ids[t] = id;
    }
    __syncthreads();
    int cnt = 0;
    if (t < BB*NN) {
        int bb = t >> 5, n = t & 31;
        int id = ids[t];
        if (id != -1) for (int j = n + 1; j < NN; j++) cnt += (ids[bb*NN + j] == id);
    }
    if (cnt) atomicAdd(&total, cnt);
    __syncthreads();
    if (t == 0) out[0] = (float)total / TOTAL_PAIRS;
}

extern "C" void kernel_launch(void* const* d_in, const int* in_sizes, int n_in,
                              void* d_out, int out_size, void* d_ws, size_t ws_size,
                              hipStream_t stream) {
    const float* feat  = (const float*)d_in[0];
    const int* centers = (const int*)d_in[1];
    float* out         = (float*)d_out;
    char* ws           = (char*)d_ws;

    uint32_t* hist = (uint32_t*)(ws + OFF_HIST);
    uint32_t* thr  = (uint32_t*)(ws + OFF_THR);
    int*      Pg   = (int*)(ws + OFF_P);
    uint32_t* keys = (uint32_t*)(ws + OFF_KEYS);

    hipMemsetAsync(ws, 0, ZERO_BYTES, stream);   // hist only (16 KiB)

    dim3 gridPix(NPIX/256, BB);
    k_d2mfma    <<<gridPix, 256, 0, stream>>>(feat, centers, keys, hist, Pg);
    k_selthr    <<<BB, 1024, 0, stream>>>(keys, hist, thr);
    k_ccl       <<<HH*BB, 256, 0, stream>>>(keys, thr, Pg);
    k_pairs_fin <<<1, 256, 0, stream>>>(centers, keys, thr, Pg, out);
}

// Round 7
// 224.564 us; speedup vs baseline: 1.3153x; 1.0125x over previous
//
#include <hip/hip_runtime.h>
#include <stdint.h>

#define BB 4
#define HH 256
#define WW 256
#define CC 128
#define NN 32
#define NPIX (HH*WW)            // 65536
#define RANK 52428u             // 0-based order-stat index: 0.8*(65536-1) exactly
#define TOTAL_PAIRS 1984.0f     // B * N*(N-1)/2
#define CAND_MAX 8192u

// workspace layout: only hist needs zeroing (16 KiB memset). P is zeroed inline by K0.
// P uses biased parents: stored 0 = sentinel (self-root or background), else parent+1.
#define OFF_HIST 0                               // BB*1024 u32 = 16 KiB (zeroed)
#define ZERO_BYTES (BB*1024*4)
#define OFF_THR  ZERO_BYTES                      // BB u32 (always written)
#define OFF_P    (OFF_THR + 64)                  // BB*NPIX i32 = 1 MiB (zeroed by K0)
#define OFF_KEYS (OFF_P + BB*NPIX*4)             // BB*NPIX u32 = 1 MiB

typedef __attribute__((ext_vector_type(8))) short short8;
typedef __attribute__((ext_vector_type(4))) float f32x4;

// 3-way bf16 split via truncation; residual <= 2^-24 |f|.
__device__ __forceinline__ void split3(float f, short &hi, short &mid, short &lo) {
    uint32_t u  = __float_as_uint(f);
    uint32_t hb = u & 0xffff0000u;
    hi = (short)(hb >> 16);
    float r1 = f - __uint_as_float(hb);
    uint32_t mb = __float_as_uint(r1) & 0xffff0000u;
    mid = (short)(mb >> 16);
    float r2 = r1 - __uint_as_float(mb);
    lo = (short)(__float_as_uint(r2) >> 16);
}

// quantized bin: monotone nondecreasing in d2 (x128 exact pow2 scale) -> exact select.
__device__ __forceinline__ uint32_t qbin_of(uint32_t keybits) {
    float f = __uint_as_float(keybits);
    return (uint32_t)fminf(f * 128.0f, 65535.0f);
}

// ---------------- K0: MFMA min squared distance -> keys + coarse hist + P zeroing -----
// block = 256 threads = 4 waves; each wave loops 4 tiles of 16 pixels => 256 px/block.
// Channel remap c = q*32 + kk*8 (A lane reads ONE contiguous 128-B line per tile;
// B staging permuted to match) + explicit 1-deep register prefetch of the next tile.
__global__ __launch_bounds__(256) void k_d2mfma(const float* __restrict__ feat,
        const int* __restrict__ centers, uint32_t* __restrict__ keys,
        uint32_t* __restrict__ hist, int* __restrict__ Pg) {
    __shared__ short gB[12288];      // 24 KiB: [t*4+kk][lane][8]
    __shared__ float gpart[32][8];
    __shared__ float gnormL[32];
    __shared__ uint32_t lhist[1024];
    int b = blockIdx.y;
    int tid = threadIdx.x;

    // zero this block's P slice (dense coalesced; consumed only after kernel boundary)
    Pg[(b << 16) + blockIdx.x*256 + tid] = 0;

    #pragma unroll
    for (int j = 0; j < 4; j++) lhist[tid + j*256] = 0u;

    // ---- inline gather: thread (n = tid&31, j0 = tid>>5) owns center n, cols [j0*16,+16)
    // channel c = j0*16 + hh*8 + u  ->  (q = c>>5, kk = (c>>3)&3): q = j0>>1, kk = (j0&1)*2+hh
    {
        int n = tid & 31, j0 = tid >> 5;
        int cy = centers[(b*NN + n)*2 + 0];
        int cx = centers[(b*NN + n)*2 + 1];
        const float* gp = feat + ((size_t)(b << 16) + cy*WW + cx)*CC + j0*16;
        int tt = n >> 4, lane16 = n & 15, q_ = j0 >> 1, kkb = (j0 & 1)*2;
        float ss = 0.f;
        #pragma unroll
        for (int hh = 0; hh < 2; hh++) {         // kk = kkb + hh
            short8 vhi, vmid, vlo;
            #pragma unroll
            for (int u = 0; u < 8; u++) {
                float f = gp[hh*8 + u];
                ss = fmaf(f, f, ss);
                short a, bm, c; split3(f, a, bm, c);
                vhi[u] = a; vmid[u] = bm; vlo[u] = c;
            }
            int lane = q_*16 + lane16;
            int off = (tt*4 + kkb + hh)*512 + lane*8;  // shorts; 16B-aligned contiguous
            *(short8*)&gB[off]        = vhi;
            *(short8*)&gB[off + 4096] = vmid;
            *(short8*)&gB[off + 8192] = vlo;
        }
        gpart[n][j0] = ss;
    }
    __syncthreads();
    if (tid < 32) {
        float s = 0.f;
        #pragma unroll
        for (int j = 0; j < 8; j++) s += gpart[tid][j];
        gnormL[tid] = s;
    }
    __syncthreads();

    int wv = tid >> 6, L = tid & 63;
    int m = L & 15, q = L >> 4;
    float gn0 = gnormL[m];
    float gn1 = gnormL[16 + m];

    // lane (m,q) reads channels [q*32, q*32+32) of its pixel: one 128-B line, 8 float4.
    const float* fpl = feat + ((size_t)(b << 16) + blockIdx.x*256 + m)*CC + q*32;

    float4 pf[8];
    {
        const float* f0 = fpl + (size_t)(wv*4)*16*CC;
        #pragma unroll
        for (int j = 0; j < 8; j++) pf[j] = *(const float4*)(f0 + j*4);
    }

    #pragma unroll
    for (int it = 0; it < 4; it++) {
        int p0 = blockIdx.x*256 + (wv*4 + it)*16;

        // prefetch next tile's 128 B while computing this one
        float4 nf[8];
        if (it < 3) {
            const float* f1 = fpl + (size_t)(wv*4 + it + 1)*16*CC;
            #pragma unroll
            for (int j = 0; j < 8; j++) nf[j] = *(const float4*)(f1 + j*4);
        }

        f32x4 acc[2] = {{0.f,0.f,0.f,0.f},{0.f,0.f,0.f,0.f}};
        float fn = 0.f;

        #pragma unroll
        for (int kk = 0; kk < 4; kk++) {
            float4 fa = pf[kk*2];
            float4 fb = pf[kk*2 + 1];
            float fs[8] = {fa.x,fa.y,fa.z,fa.w,fb.x,fb.y,fb.z,fb.w};
            short8 ahi, amid, alo;
            #pragma unroll
            for (int j = 0; j < 8; j++) {
                float f = fs[j];
                fn = fmaf(f, f, fn);
                short hh, md, lw; split3(f, hh, md, lw);
                ahi[j] = hh; amid[j] = md; alo[j] = lw;
            }
            #pragma unroll
            for (int t = 0; t < 2; t++) {
                int off = (t*4 + kk)*512 + L*8;
                short8 bhi = *(const short8*)&gB[off];
                short8 bmd = *(const short8*)&gB[off + 4096];
                short8 blo = *(const short8*)&gB[off + 8192];
                // 6 significant split products
                acc[t] = __builtin_amdgcn_mfma_f32_16x16x32_bf16(ahi,  bhi, acc[t], 0,0,0);
                acc[t] = __builtin_amdgcn_mfma_f32_16x16x32_bf16(ahi,  bmd, acc[t], 0,0,0);
                acc[t] = __builtin_amdgcn_mfma_f32_16x16x32_bf16(amid, bhi, acc[t], 0,0,0);
                acc[t] = __builtin_amdgcn_mfma_f32_16x16x32_bf16(ahi,  blo, acc[t], 0,0,0);
                acc[t] = __builtin_amdgcn_mfma_f32_16x16x32_bf16(amid, bmd, acc[t], 0,0,0);
                acc[t] = __builtin_amdgcn_mfma_f32_16x16x32_bf16(alo,  bhi, acc[t], 0,0,0);
            }
        }

        fn += __shfl_xor(fn, 16);
        fn += __shfl_xor(fn, 32);

        // C layout: col(n) = L&15, row(pixel) = q*4 + reg
        float vmin[4];
        #pragma unroll
        for (int r = 0; r < 4; r++) {
            float fnr = __shfl(fn, q*4 + r);
            float d0 = fnr + gn0 - 2.f*acc[0][r];
            float d1 = fnr + gn1 - 2.f*acc[1][r];
            float v = fminf(d0, d1);
            v = fminf(v, __shfl_xor(v, 1));
            v = fminf(v, __shfl_xor(v, 2));
            v = fminf(v, __shfl_xor(v, 4));
            v = fminf(v, __shfl_xor(v, 8));
            vmin[r] = v;
        }
        if (m < 4) {
            float v = (m==0) ? vmin[0] : (m==1) ? vmin[1] : (m==2) ? vmin[2] : vmin[3];
            if (!(v > 0.f)) v = 0.f;     // clamp negatives and -0.0
            uint32_t kb = __float_as_uint(v);
            keys[(size_t)(b << 16) + p0 + q*4 + m] = kb;
            atomicAdd(&lhist[qbin_of(kb) >> 6], 1u);
        }

        if (it < 3) {
            #pragma unroll
            for (int j = 0; j < 8; j++) pf[j] = nf[j];
        }
    }

    __syncthreads();
    #pragma unroll
    for (int j = 0; j < 4; j++) {
        int bin = tid + j*256;
        uint32_t hv = lhist[bin];
        if (hv) atomicAdd(&hist[(b << 10) + bin], hv);
    }
}

// ---------------- K1: single-pass select -> exact threshold key bits ----------------
// one block (1024 thr) per batch. Coarse select from precomputed hist (no key pass),
// then ONE key pass collecting fine hist + coarse-bin candidates simultaneously,
// then compact bin-T candidates (~tens) and exact duplicate-safe rank among them.
__global__ __launch_bounds__(1024) void k_selthr(const uint32_t* __restrict__ keys,
        const uint32_t* __restrict__ hist, uint32_t* __restrict__ thr_sm) {
    int b = blockIdx.x, t = threadIdx.x;
    __shared__ uint32_t wsum[16];
    __shared__ uint32_t sT1, sR1, sT, sR2, scnt, scnt2;
    __shared__ uint32_t fh[64];
    __shared__ uint32_t cand[CAND_MAX];
    __shared__ uint32_t cand2[2048];

    if (t < 64) fh[t] = 0;
    if (t == 0) { scnt = 0; scnt2 = 0; }

    // coarse select T1: prefix over 1024 precomputed bins (wave scan + cross-wave fix)
    int lane = t & 63, w = t >> 6;
    uint32_t s = hist[(b << 10) + t];
    uint32_t inc = s;
    #pragma unroll
    for (int off = 1; off < 64; off <<= 1) {
        uint32_t nb = __shfl_up((int)inc, off);
        if (lane >= off) inc += nb;
    }
    if (lane == 63) wsum[w] = inc;
    __syncthreads();
    if (t < 16) {
        uint32_t v = wsum[t];
        #pragma unroll
        for (int off = 1; off < 16; off <<= 1) {
            uint32_t nb = __shfl_up((int)v, off);
            if (t >= off) v += nb;
        }
        wsum[t] = v;
    }
    __syncthreads();
    uint32_t pre = ((w == 0) ? 0u : wsum[w-1]) + inc - s;
    if (pre <= RANK && RANK < pre + s) { sT1 = (uint32_t)t; sR1 = RANK - pre; }
    __syncthreads();
    uint32_t T1 = sT1, r1 = sR1;

    // single pass: fine hist (qbin&63) + candidate collection for qbin>>6 == T1
    const uint4* kb = (const uint4*)(keys + ((size_t)b << 16));
    for (int i = t; i < NPIX/4; i += 1024) {
        uint4 k = kb[i];
        uint32_t q;
        #define PROC_KEY(X) { q = qbin_of(X); if ((q >> 6) == T1) { \
            atomicAdd(&fh[q & 63u], 1u); \
            uint32_t p = atomicAdd(&scnt, 1u); \
            if (p < CAND_MAX) cand[p] = (X); } }
        PROC_KEY(k.x) PROC_KEY(k.y) PROC_KEY(k.z) PROC_KEY(k.w)
        #undef PROC_KEY
    }
    __syncthreads();

    // fine select T
    if (t < 64) {
        uint32_t s2 = fh[t];
        uint32_t inc2 = s2;
        #pragma unroll
        for (int off = 1; off < 64; off <<= 1) {
            uint32_t nb = __shfl_up((int)inc2, off);
            if (t >= off) inc2 += nb;
        }
        uint32_t pre2 = inc2 - s2;
        if (pre2 <= r1 && r1 < pre2 + s2) { sT = (T1 << 6) | (uint32_t)t; sR2 = r1 - pre2; }
    }
    __syncthreads();
    uint32_t T = sT, r2 = sR2;
    uint32_t K = scnt; if (K > CAND_MAX) K = CAND_MAX;

    // compact bin-T candidates (expected ~tens)
    for (uint32_t i = t; i < K; i += 1024) {
        uint32_t v = cand[i];
        if (qbin_of(v) == T) { uint32_t p = atomicAdd(&scnt2, 1u); if (p < 2048u) cand2[p] = v; }
    }
    __syncthreads();
    uint32_t K2 = scnt2; if (K2 > 2048u) K2 = 2048u;

    // exact rank among bin-T candidates (duplicate-safe)
    for (uint32_t i = t; i < K2; i += 1024) {
        uint32_t v = cand2[i];
        uint32_t less = 0, eq = 0;
        for (uint32_t j = 0; j < K2; j++) { uint32_t x = cand2[j]; less += (x < v); eq += (x == v); }
        if (less <= r2 && r2 < less + eq) thr_sm[b] = v;   // all writers agree
    }
}

// ---------------- union-find with biased parents (0 = self-root sentinel) ----------
// parent pointers always point to smaller indices -> chains strictly decrease, no cycles.
__device__ __forceinline__ int uf_find(int* P, int x) {
    while (true) {
        int v = P[x];
        if (v == 0) return x;
        int p = v - 1;
        int gv = P[p];
        if (gv == 0) return p;
        P[x] = gv;             // path halving (benign race, always a valid ancestor link)
        x = gv - 1;
    }
}
__device__ __forceinline__ void uf_unite(int* P, int a, int b) {
    while (true) {
        a = uf_find(P, a);
        b = uf_find(P, b);
        if (a == b) return;
        if (a > b) { int t = a; a = b; b = t; }
        int old = atomicCAS(&P[b], 0, a + 1);   // device-scope
        if (old == 0) return;
        b = old - 1;
    }
}

// ---------------- K2: fused CCL: on-the-fly run-starts + unions (NO gate) -------------
// block = one image row (1024 blocks). Run-start labels are a pure function of keys,
// recomputed for own row and the row above -> no separate init kernel needed.
// P stores: non-run-start masked pixels get P[p]=runstart+1 (plain store; these addresses
// are never touched by CAS/path-halving, which traverse run-start nodes only).
__global__ __launch_bounds__(256) void k_ccl(const uint32_t* __restrict__ keys,
        const uint32_t* __restrict__ thr_sm, int* __restrict__ Pg) {
    int bid = blockIdx.x;
    int b = bid >> 8, rr = bid & 255;
    int x = threadIdx.x;
    __shared__ int up_rs[256];     // upper row: global run-start index, or -1 if unmasked
    __shared__ int swtmp[4];

    uint32_t thrv = thr_sm[b];
    int* P = Pg + (b << 16);
    int p = (rr << 8) + x;
    bool msk = keys[((size_t)b << 16) + p] >= thrv;
    int lane = x & 63, w = x >> 6;

    // scan own row: nearest unmasked index <= x  ->  run start = acc+1
    int v = msk ? -1 : x;
    #pragma unroll
    for (int off = 1; off < 64; off <<= 1) {
        int nb = __shfl_up(v, off);
        if (lane >= off) v = max(v, nb);
    }
    if (lane == 63) swtmp[w] = v;
    __syncthreads();
    int acc = v;
    for (int i = 0; i < w; i++) acc = max(acc, swtmp[i]);
    int rs = (rr << 8) + acc + 1;            // valid only when msk
    __syncthreads();                          // before reusing swtmp

    if (rr > 0) {
        bool msku = keys[((size_t)b << 16) + p - WW] >= thrv;
        int vu = msku ? -1 : x;
        #pragma unroll
        for (int off = 1; off < 64; off <<= 1) {
            int nb = __shfl_up(vu, off);
            if (lane >= off) vu = max(vu, nb);
        }
        if (lane == 63) swtmp[w] = vu;
        __syncthreads();
        int accu = vu;
        for (int i = 0; i < w; i++) accu = max(accu, swtmp[i]);
        up_rs[x] = msku ? (((rr - 1) << 8) + accu + 1) : -1;
    }

    if (msk && rs != p) P[p] = rs + 1;       // init store (disjoint from CAS targets)
    __syncthreads();                          // up_rs ready

    if (rr > 0 && msk) {
        bool ul = (x > 0)   && up_rs[x-1] >= 0;
        bool uu =              up_rs[x]   >= 0;
        bool ur = (x < 255) && up_rs[x+1] >= 0;
        if (ul)        uf_unite(P, rs, up_rs[x-1]);
        if (uu && !ul) uf_unite(P, rs, up_rs[x]);
        if (ur && !uu) uf_unite(P, rs, up_rs[x+1]);
    }
}

// ---------------- K3: merged pairs at centers + output ----------------
__global__ void k_pairs_fin(const int* __restrict__ centers,
        const uint32_t* __restrict__ keys, const uint32_t* __restrict__ thr_sm,
        const int* __restrict__ Pg, float* __restrict__ out) {
    __shared__ int ids[BB*NN];
    __shared__ int total;
    int t = threadIdx.x;
    if (t == 0) total = 0;
    __syncthreads();
    if (t < BB*NN) {
        int bb = t >> 5;
        int cy = centers[t*2 + 0];
        int cx = centers[t*2 + 1];
        int pp = cy*WW + cx;
        const int* Pb = Pg + (bb << 16);
        int id = -1;
        if (keys[((size_t)bb << 16) + pp] >= thr_sm[bb]) {
            int xx = pp;
            while (true) { int vv = Pb[xx]; if (vv == 0) break; xx = vv - 1; }
            id = xx;
        }
        ids[t] = id;
    }
    __syncthreads();
    int cnt = 0;
    if (t < BB*NN) {
        int bb = t >> 5, n = t & 31;
        int id = ids[t];
        if (id != -1) for (int j = n + 1; j < NN; j++) cnt += (ids[bb*NN + j] == id);
    }
    if (cnt) atomicAdd(&total, cnt);
    __syncthreads();
    if (t == 0) out[0] = (float)total / TOTAL_PAIRS;
}

extern "C" void kernel_launch(void* const* d_in, const int* in_sizes, int n_in,
                              void* d_out, int out_size, void* d_ws, size_t ws_size,
                              hipStream_t stream) {
    const float* feat  = (const float*)d_in[0];
    const int* centers = (const int*)d_in[1];
    float* out         = (float*)d_out;
    char* ws           = (char*)d_ws;

    uint32_t* hist = (uint32_t*)(ws + OFF_HIST);
    uint32_t* thr  = (uint32_t*)(ws + OFF_THR);
    int*      Pg   = (int*)(ws + OFF_P);
    uint32_t* keys = (uint32_t*)(ws + OFF_KEYS);

    hipMemsetAsync(ws, 0, ZERO_BYTES, stream);   // hist only (16 KiB)

    dim3 gridPix(NPIX/256, BB);
    k_d2mfma    <<<gridPix, 256, 0, stream>>>(feat, centers, keys, hist, Pg);
    k_selthr    <<<BB, 1024, 0, stream>>>(keys, hist, thr);
    k_ccl       <<<HH*BB, 256, 0, stream>>>(keys, thr, Pg);
    k_pairs_fin <<<1, 256, 0, stream>>>(centers, keys, thr, Pg, out);
}